// Round 8
// baseline (131.469 us; speedup 1.0000x reference)
//
#include <hip/hip_runtime.h>

#define T_SEQ 4096
#define NBATCH 2
#define DM 1024
#define DI 32
#define NH 4
#define NCOLS 164      // 128 q + 32 k + 4 w
#define NCOLS_PAD 192  // 12 tiles of 16

typedef __attribute__((ext_vector_type(8))) short bf16x8;
typedef __attribute__((ext_vector_type(4))) float f32x4;

__device__ __forceinline__ unsigned short f2bf(float f) {
    unsigned int u = __builtin_bit_cast(unsigned int, f);
    u += 0x7FFFu + ((u >> 16) & 1u);   // RNE; inputs have no NaN
    return (unsigned short)(u >> 16);
}

// ---------------- prep: W^T -> bf16 [192][1024], bias[192] ----------------
// (bit-identical to R4)
__global__ __launch_bounds__(256) void prep_kernel(
    const float* __restrict__ Wq, const float* __restrict__ bq,
    const float* __restrict__ Wk, const float* __restrict__ bk,
    const float* __restrict__ Ww, const float* __restrict__ bw,
    unsigned short* __restrict__ WT, float* __restrict__ bias) {
    int c = blockIdx.x;                    // 0..191
    const float* src = nullptr; int stride = 0; float bv = 0.f;
    if (c < 128)      { src = Wq + c;       stride = NH * DI; bv = bq[c]; }
    else if (c < 160) { src = Wk + (c-128); stride = DI;      bv = bk[c-128]; }
    else if (c < 164) { src = Ww + (c-160); stride = NH;      bv = bw[c-160]; }
    for (int k = threadIdx.x; k < DM; k += blockDim.x) {
        float v = src ? src[(size_t)k * stride] : 0.f;
        WT[(size_t)c * DM + k] = f2bf(v);
    }
    if (threadIdx.x == 0) bias[c] = bv;
}

// ---------------- projection: [8192 x 192] = x[8192 x 1024] * W ----------------
// (bit-identical to R4)
__global__ __launch_bounds__(256) void proj_kernel(
    const float* __restrict__ x, const unsigned short* __restrict__ WT,
    const float* __restrict__ bias,
    unsigned short* __restrict__ qws, unsigned short* __restrict__ kws,
    float* __restrict__ wws) {
    __shared__ unsigned short afrag[32 * 512];   // 32 KB
    int wave = threadIdx.x >> 6;
    int lane = threadIdx.x & 63;
    int lr = lane & 15, kg = lane >> 4;
    int r0 = blockIdx.x * 16;

    int rowA = r0 + lr;
    int tA = rowA & (T_SEQ - 1), bA = rowA >> 12;
    const float* xrow = x + ((size_t)tA * NBATCH + bA) * DM;

    #pragma unroll
    for (int j = 0; j < 8; ++j) {
        int c = wave * 8 + j;
        const float* xp = xrow + c * 32 + kg * 8;
        f32x4 a0 = *(const f32x4*)xp;
        f32x4 a1 = *(const f32x4*)(xp + 4);
        bf16x8 af;
        af[0] = (short)f2bf(a0[0]); af[1] = (short)f2bf(a0[1]);
        af[2] = (short)f2bf(a0[2]); af[3] = (short)f2bf(a0[3]);
        af[4] = (short)f2bf(a1[0]); af[5] = (short)f2bf(a1[1]);
        af[6] = (short)f2bf(a1[2]); af[7] = (short)f2bf(a1[3]);
        *(bf16x8*)(&afrag[c * 512 + lane * 8]) = af;
    }
    __syncthreads();

    int ct0 = wave * 3;
    f32x4 acc[3] = {};
    #pragma unroll 2
    for (int c = 0; c < 32; ++c) {
        bf16x8 af = *(const bf16x8*)(&afrag[c * 512 + lane * 8]);
        int k0 = c * 32;
        #pragma unroll
        for (int i = 0; i < 3; ++i) {
            int col = (ct0 + i) * 16 + lr;
            bf16x8 bfg = *(const bf16x8*)(WT + (size_t)col * DM + k0 + kg * 8);
            acc[i] = __builtin_amdgcn_mfma_f32_16x16x32_bf16(af, bfg, acc[i], 0, 0, 0);
        }
    }

    #pragma unroll
    for (int i = 0; i < 3; ++i) {
        int cout = (ct0 + i) * 16 + lr;
        float bv = bias[cout];
        #pragma unroll
        for (int r = 0; r < 4; ++r) {
            int rr = r0 + kg * 4 + r;
            int tt = rr & (T_SEQ - 1), bb = rr >> 12;
            float v = acc[i][r] + bv;
            size_t rowoff = (size_t)bb * T_SEQ + tt;
            if (cout < 128)       qws[rowoff * 128 + cout] = f2bf(v);
            else if (cout < 160)  kws[rowoff * 32 + (cout - 128)] = f2bf(v);
            else if (cout < 164)  wws[rowoff * 4 + (cout - 160)] = v;
        }
    }
}

// ---------------- main: out[b][t][s] = sum_h relu(q_h . k) * w_h ----------------
// (bit-identical to R4; warm ~32.5 us measured in R5)
__global__ __launch_bounds__(256) void indexer_kernel(
    const unsigned short* __restrict__ qws, const unsigned short* __restrict__ kws,
    const float* __restrict__ wws, float* __restrict__ out) {
    int wave = threadIdx.x >> 6;
    int lane = threadIdx.x & 63;
    int gw = blockIdx.x * 4 + wave;        // 0..8191
    int strip = gw & 15;
    int t16 = (gw >> 4) & 255;
    int b = gw >> 12;
    int t0 = t16 * 16;
    int lr = lane & 15, kg = lane >> 4;

    const unsigned short* qrow = qws + ((size_t)b * T_SEQ + t0 + lr) * 128;
    bf16x8 qf[4];
    #pragma unroll
    for (int h = 0; h < 4; ++h)
        qf[h] = *(const bf16x8*)(qrow + h * 32 + kg * 8);

    f32x4 w4 = *(const f32x4*)(wws + ((size_t)b * T_SEQ + t0 + lr) * 4);

    float* outrow = out + (size_t)b * T_SEQ * T_SEQ + (size_t)(t0 + lr) * T_SEQ;
    const unsigned short* kbase = kws + (size_t)b * T_SEQ * 32;
    int sbase = strip * 256;

    for (int g = 0; g < 4; ++g) {
        int s0 = sbase + g * 64;
        bf16x8 kf0 = *(const bf16x8*)(kbase + (size_t)(s0      + lr) * 32 + kg * 8);
        bf16x8 kf1 = *(const bf16x8*)(kbase + (size_t)(s0 + 16 + lr) * 32 + kg * 8);
        bf16x8 kf2 = *(const bf16x8*)(kbase + (size_t)(s0 + 32 + lr) * 32 + kg * 8);
        bf16x8 kf3 = *(const bf16x8*)(kbase + (size_t)(s0 + 48 + lr) * 32 + kg * 8);
        f32x4 z = {0.f, 0.f, 0.f, 0.f};
        f32x4 v[4];
        #pragma unroll
        for (int j = 0; j < 4; ++j) {
            bf16x8 kf = (j == 0) ? kf0 : (j == 1) ? kf1 : (j == 2) ? kf2 : kf3;
            f32x4 a0 = __builtin_amdgcn_mfma_f32_16x16x32_bf16(kf, qf[0], z, 0, 0, 0);
            f32x4 a1 = __builtin_amdgcn_mfma_f32_16x16x32_bf16(kf, qf[1], z, 0, 0, 0);
            f32x4 a2 = __builtin_amdgcn_mfma_f32_16x16x32_bf16(kf, qf[2], z, 0, 0, 0);
            f32x4 a3 = __builtin_amdgcn_mfma_f32_16x16x32_bf16(kf, qf[3], z, 0, 0, 0);
            #pragma unroll
            for (int r = 0; r < 4; ++r) {
                v[j][r] = fmaxf(a0[r], 0.f) * w4[0] + fmaxf(a1[r], 0.f) * w4[1]
                        + fmaxf(a2[r], 0.f) * w4[2] + fmaxf(a3[r], 0.f) * w4[3];
            }
        }
        #pragma unroll
        for (int j = 0; j < 4; ++j)
            *(f32x4*)(outrow + s0 + j * 16 + kg * 4) = v[j];
    }
}

extern "C" void kernel_launch(void* const* d_in, const int* in_sizes, int n_in,
                              void* d_out, int out_size, void* d_ws, size_t ws_size,
                              hipStream_t stream) {
    const float* x  = (const float*)d_in[0];
    const float* Wq = (const float*)d_in[1];
    const float* bq = (const float*)d_in[2];
    const float* Wk = (const float*)d_in[3];
    const float* bk = (const float*)d_in[4];
    const float* Ww = (const float*)d_in[5];
    const float* bw = (const float*)d_in[6];
    float* out = (float*)d_out;

    char* ws = (char*)d_ws;
    unsigned short* WT  = (unsigned short*)(ws);            // 192*1024*2 = 393216 B
    float* bias         = (float*)(ws + 393216);            // 768 B
    unsigned short* qws = (unsigned short*)(ws + 524288);   // 2 MB
    unsigned short* kws = (unsigned short*)(ws + 2621440);  // 512 KB
    float* wws          = (float*)(ws + 3145728);           // 128 KB

    // Timing probe round: prep x3 and proj x3 (idempotent).
    // dur = 71.9 + 2*(P0+P1); separates "proj is slow" from "replay overhead".
    prep_kernel<<<dim3(NCOLS_PAD), dim3(256), 0, stream>>>(Wq, bq, Wk, bk, Ww, bw, WT, bias);
    prep_kernel<<<dim3(NCOLS_PAD), dim3(256), 0, stream>>>(Wq, bq, Wk, bk, Ww, bw, WT, bias);
    prep_kernel<<<dim3(NCOLS_PAD), dim3(256), 0, stream>>>(Wq, bq, Wk, bk, Ww, bw, WT, bias);
    proj_kernel<<<dim3(512), dim3(256), 0, stream>>>(x, WT, bias, qws, kws, wws);
    proj_kernel<<<dim3(512), dim3(256), 0, stream>>>(x, WT, bias, qws, kws, wws);
    proj_kernel<<<dim3(512), dim3(256), 0, stream>>>(x, WT, bias, qws, kws, wws);
    indexer_kernel<<<dim3(2048), dim3(256), 0, stream>>>(qws, kws, wws, out);
}

// Round 9
// 58.057 us; speedup vs baseline: 2.2645x; 2.2645x over previous
//
#include <hip/hip_runtime.h>

#define T_SEQ 4096
#define NBATCH 2
#define DM 1024
#define DI 32
#define NH 4
#define NCOLS 164      // 128 q + 32 k + 4 w
#define NCOLS_PAD 192  // 12 tiles of 16
#define KC 64          // K-chunk for proj v2
#define BSTRIDE 72     // shorts per col-slice in LDS (64 + 8 pad -> 2-way banks)

typedef __attribute__((ext_vector_type(8))) short bf16x8;
typedef __attribute__((ext_vector_type(4))) float f32x4;

__device__ __forceinline__ unsigned short f2bf(float f) {
    unsigned int u = __builtin_bit_cast(unsigned int, f);
    u += 0x7FFFu + ((u >> 16) & 1u);   // RNE; inputs have no NaN
    return (unsigned short)(u >> 16);
}

// ---------------- prep: W^T -> bf16 [192][1024], bias[192] ----------------
// (bit-identical to R4)
__global__ __launch_bounds__(256) void prep_kernel(
    const float* __restrict__ Wq, const float* __restrict__ bq,
    const float* __restrict__ Wk, const float* __restrict__ bk,
    const float* __restrict__ Ww, const float* __restrict__ bw,
    unsigned short* __restrict__ WT, float* __restrict__ bias) {
    int c = blockIdx.x;                    // 0..191
    const float* src = nullptr; int stride = 0; float bv = 0.f;
    if (c < 128)      { src = Wq + c;       stride = NH * DI; bv = bq[c]; }
    else if (c < 160) { src = Wk + (c-128); stride = DI;      bv = bk[c-128]; }
    else if (c < 164) { src = Ww + (c-160); stride = NH;      bv = bw[c-160]; }
    for (int k = threadIdx.x; k < DM; k += blockDim.x) {
        float v = src ? src[(size_t)k * stride] : 0.f;
        WT[(size_t)c * DM + k] = f2bf(v);
    }
    if (threadIdx.x == 0) bias[c] = bv;
}

// ---------------- projection v2: LDS-staged, double-buffered ----------------
// Block = 16 rows; 16 K-chunks of 64. Per chunk: stage B-slice (192x64 bf16,
// padded stride) + A-frags into LDS via issue-early/write-late split (T14),
// then each wave does 8 ds_read_b128 + 6 MFMA. One barrier per chunk.
__global__ __launch_bounds__(256) void proj_kernel(
    const float* __restrict__ x, const unsigned short* __restrict__ WT,
    const float* __restrict__ bias,
    unsigned short* __restrict__ qws, unsigned short* __restrict__ kws,
    float* __restrict__ wws) {
    __shared__ unsigned short Bb[2][NCOLS_PAD * BSTRIDE];  // 2 x 27648 B
    __shared__ unsigned short Ab[2][1024];                 // 2 x 2048 B
    int t = threadIdx.x;
    int wave = t >> 6, lane = t & 63;
    int lr = lane & 15, kg = lane >> 4;
    int r0 = blockIdx.x * 16;

    // A-staging mapping: thread covers 4 floats of the fragment layout
    int akk = t >> 7, alane = (t & 127) >> 1, ahalf = t & 1;
    int arow = alane & 15, akg = alane >> 4;
    int rowA = r0 + arow;
    int tA = rowA & (T_SEQ - 1), bA = rowA >> 12;
    const float* xrowA = x + ((size_t)tA * NBATCH + bA) * DM;

    bf16x8 breg[6];     // staged B in flight
    f32x4  areg;        // staged A in flight

    auto STAGE_LOAD = [&](int c) {
        int k0 = c * KC;
        #pragma unroll
        for (int it = 0; it < 6; ++it) {
            int tau = it * 256 + t;
            int col = tau >> 3, jg = tau & 7;   // col 0..191, 8 groups of 8 shorts
            breg[it] = *(const bf16x8*)(WT + (size_t)col * DM + k0 + jg * 8);
        }
        areg = *(const f32x4*)(xrowA + k0 + akk * 32 + akg * 8 + ahalf * 4);
    };
    auto STAGE_WRITE = [&](int buf) {
        #pragma unroll
        for (int it = 0; it < 6; ++it) {
            int tau = it * 256 + t;
            int col = tau >> 3, jg = tau & 7;
            *(bf16x8*)(&Bb[buf][col * BSTRIDE + jg * 8]) = breg[it];
        }
        unsigned short* d = &Ab[buf][akk * 512 + alane * 8 + ahalf * 4];
        d[0] = f2bf(areg[0]); d[1] = f2bf(areg[1]);
        d[2] = f2bf(areg[2]); d[3] = f2bf(areg[3]);
    };

    STAGE_LOAD(0);
    STAGE_WRITE(0);
    __syncthreads();

    int ct0 = wave * 3;                  // 3 col-tiles per wave, branch-free
    f32x4 acc[3] = {};
    for (int c = 0; c < 16; ++c) {
        int buf = c & 1;
        if (c < 15) STAGE_LOAD(c + 1);   // issue early (hides under MFMA)
        #pragma unroll
        for (int kk = 0; kk < 2; ++kk) {
            bf16x8 af = *(const bf16x8*)(&Ab[buf][kk * 512 + lane * 8]);
            #pragma unroll
            for (int i = 0; i < 3; ++i) {
                int col = (ct0 + i) * 16 + lr;
                bf16x8 bfg = *(const bf16x8*)(&Bb[buf][col * BSTRIDE + kk * 32 + kg * 8]);
                acc[i] = __builtin_amdgcn_mfma_f32_16x16x32_bf16(af, bfg, acc[i], 0, 0, 0);
            }
        }
        if (c < 15) STAGE_WRITE(buf ^ 1); // write late (other buffer; pre-barrier)
        __syncthreads();
    }

    // epilogue: D col = lane&15, row = (lane>>4)*4 + reg  (bit-identical to R4)
    #pragma unroll
    for (int i = 0; i < 3; ++i) {
        int cout = (ct0 + i) * 16 + lr;
        float bv = bias[cout];
        #pragma unroll
        for (int r = 0; r < 4; ++r) {
            int rr = r0 + kg * 4 + r;
            int tt = rr & (T_SEQ - 1), bb = rr >> 12;
            float v = acc[i][r] + bv;
            size_t rowoff = (size_t)bb * T_SEQ + tt;
            if (cout < 128)       qws[rowoff * 128 + cout] = f2bf(v);
            else if (cout < 160)  kws[rowoff * 32 + (cout - 128)] = f2bf(v);
            else if (cout < 164)  wws[rowoff * 4 + (cout - 160)] = v;
        }
    }
}

// ---------------- main: out[b][t][s] = sum_h relu(q_h . k) * w_h ----------------
// (bit-identical to R4; warm ~32.5 us measured in R5)
__global__ __launch_bounds__(256) void indexer_kernel(
    const unsigned short* __restrict__ qws, const unsigned short* __restrict__ kws,
    const float* __restrict__ wws, float* __restrict__ out) {
    int wave = threadIdx.x >> 6;
    int lane = threadIdx.x & 63;
    int gw = blockIdx.x * 4 + wave;        // 0..8191
    int strip = gw & 15;
    int t16 = (gw >> 4) & 255;
    int b = gw >> 12;
    int t0 = t16 * 16;
    int lr = lane & 15, kg = lane >> 4;

    const unsigned short* qrow = qws + ((size_t)b * T_SEQ + t0 + lr) * 128;
    bf16x8 qf[4];
    #pragma unroll
    for (int h = 0; h < 4; ++h)
        qf[h] = *(const bf16x8*)(qrow + h * 32 + kg * 8);

    f32x4 w4 = *(const f32x4*)(wws + ((size_t)b * T_SEQ + t0 + lr) * 4);

    float* outrow = out + (size_t)b * T_SEQ * T_SEQ + (size_t)(t0 + lr) * T_SEQ;
    const unsigned short* kbase = kws + (size_t)b * T_SEQ * 32;
    int sbase = strip * 256;

    for (int g = 0; g < 4; ++g) {
        int s0 = sbase + g * 64;
        bf16x8 kf0 = *(const bf16x8*)(kbase + (size_t)(s0      + lr) * 32 + kg * 8);
        bf16x8 kf1 = *(const bf16x8*)(kbase + (size_t)(s0 + 16 + lr) * 32 + kg * 8);
        bf16x8 kf2 = *(const bf16x8*)(kbase + (size_t)(s0 + 32 + lr) * 32 + kg * 8);
        bf16x8 kf3 = *(const bf16x8*)(kbase + (size_t)(s0 + 48 + lr) * 32 + kg * 8);
        f32x4 z = {0.f, 0.f, 0.f, 0.f};
        f32x4 v[4];
        #pragma unroll
        for (int j = 0; j < 4; ++j) {
            bf16x8 kf = (j == 0) ? kf0 : (j == 1) ? kf1 : (j == 2) ? kf2 : kf3;
            f32x4 a0 = __builtin_amdgcn_mfma_f32_16x16x32_bf16(kf, qf[0], z, 0, 0, 0);
            f32x4 a1 = __builtin_amdgcn_mfma_f32_16x16x32_bf16(kf, qf[1], z, 0, 0, 0);
            f32x4 a2 = __builtin_amdgcn_mfma_f32_16x16x32_bf16(kf, qf[2], z, 0, 0, 0);
            f32x4 a3 = __builtin_amdgcn_mfma_f32_16x16x32_bf16(kf, qf[3], z, 0, 0, 0);
            #pragma unroll
            for (int r = 0; r < 4; ++r) {
                v[j][r] = fmaxf(a0[r], 0.f) * w4[0] + fmaxf(a1[r], 0.f) * w4[1]
                        + fmaxf(a2[r], 0.f) * w4[2] + fmaxf(a3[r], 0.f) * w4[3];
            }
        }
        #pragma unroll
        for (int j = 0; j < 4; ++j)
            *(f32x4*)(outrow + s0 + j * 16 + kg * 4) = v[j];
    }
}

extern "C" void kernel_launch(void* const* d_in, const int* in_sizes, int n_in,
                              void* d_out, int out_size, void* d_ws, size_t ws_size,
                              hipStream_t stream) {
    const float* x  = (const float*)d_in[0];
    const float* Wq = (const float*)d_in[1];
    const float* bq = (const float*)d_in[2];
    const float* Wk = (const float*)d_in[3];
    const float* bk = (const float*)d_in[4];
    const float* Ww = (const float*)d_in[5];
    const float* bw = (const float*)d_in[6];
    float* out = (float*)d_out;

    char* ws = (char*)d_ws;
    unsigned short* WT  = (unsigned short*)(ws);            // 192*1024*2 = 393216 B
    float* bias         = (float*)(ws + 393216);            // 768 B
    unsigned short* qws = (unsigned short*)(ws + 524288);   // 2 MB
    unsigned short* kws = (unsigned short*)(ws + 2621440);  // 512 KB
    float* wws          = (float*)(ws + 3145728);           // 128 KB

    prep_kernel<<<dim3(NCOLS_PAD), dim3(256), 0, stream>>>(Wq, bq, Wk, bk, Ww, bw, WT, bias);
    proj_kernel<<<dim3(512), dim3(256), 0, stream>>>(x, WT, bias, qws, kws, wws);
    indexer_kernel<<<dim3(2048), dim3(256), 0, stream>>>(qws, kws, wws, out);
}